// Round 10
// baseline (100.287 us; speedup 1.0000x reference)
//
#include <hip/hip_runtime.h>
#include <hip/hip_bf16.h>
#include <cstdint>

typedef __attribute__((ext_vector_type(8))) short short8;
typedef __attribute__((ext_vector_type(4))) float f32x4;

#define BDIM 32
#define CDIM 2048
#define NPIX 196    // 14*14
#define HIN 14
#define N2 784      // 28*28
#define W2 28
#define KDIM 113
#define KC 112
#define NCLS 200
#define NBX 14      // col-blocks per image
#define BNC 56      // output cols per block (2 output rows)
#define WPX 42      // window pixels (3 source rows x 14)
#define NT 3        // GEMM col tiles (48 padded)
#define PST 52      // P row stride (f32): 52%32=20, gcd-free banks
#define RDST 52     // RDs row stride
#define SST 60      // Ss row stride
#define NSTEP 64    // 2048/32

// ---------------- K_prep: concepts (+cfcw as row 113) -> bf16 pre-permuted + csq ----------------
__global__ __launch_bounds__(256) void k_prep(const float* __restrict__ concepts,
                                              const float* __restrict__ cfcw,
                                              ushort* __restrict__ cbf,
                                              float* __restrict__ csq) {
  int k = blockIdx.x, t = threadIdx.x;
  const int kt = k >> 4, lr = k & 15;
  float s = 0.f;
  for (int c = t; c < CDIM; c += 256) {
    float v = (k < KDIM) ? concepts[(size_t)k * CDIM + c] : (k == KDIM ? cfcw[c] : 0.f);
    __hip_bfloat16 h = __float2bfloat16(v);
    int st = c >> 5, gs = (c >> 3) & 3, j = c & 7;
    cbf[((((size_t)st * 8 + kt) * 4 + gs) * 16 + lr) * 8 + j] = __bfloat16_as_ushort(h);
    float vb = __bfloat162float(h);
    s = fmaf(vb, vb, s);
  }
  __shared__ float r[4];
#pragma unroll
  for (int off = 32; off > 0; off >>= 1) s += __shfl_down(s, off, 64);
  if ((t & 63) == 0) r[t >> 6] = s;
  __syncthreads();
  if (t == 0) csq[k] = r[0] + r[1] + r[2] + r[3];
}

// ---------------- K_fused: raw-pixel MFMA GEMM + Gram + output-side upsample + softmax ----------------
__global__ __launch_bounds__(512, 4) void k_fused(
    const float* __restrict__ x,         // [32][2048][14][14]
    const ushort* __restrict__ cbf,      // pre-permuted bf16 concepts (+cfcw row 113)
    const float* __restrict__ csq,       // [128]
    float* __restrict__ attn_out,        // [32][113][784]
    float* __restrict__ part)            // [32][14][112]
{
  union alignas(16) U {
    struct { float P[2][32 * PST]; ushort A[2][4096]; ushort Bf[2][NT * 512]; } l; // 35,840 B
    struct { float RDs[128 * RDST]; float Ss[KDIM * SST]; float Gpart[8 * 11 * 20]; } e; // 60,784 B
  };
  __shared__ U u;
  __shared__ float Gs[5 * 44];
  __shared__ float csq_s[KDIM];
  __shared__ float xsqs[BNC], projs[BNC];

  const int tid = threadIdx.x;
  // XCD-aware decode: all 14 col-blocks of image b on one XCD
  const int wgid = blockIdx.x;
  const int xcd = wgid & 7, slot = wgid >> 3;   // slot 0..55
  const int bq = slot / NBX;                    // 0..3
  const int bx = slot - bq * NBX;               // 0..13
  const int b = xcd + 8 * bq;
  const int n0 = bx * BNC;
  const int lane = tid & 63, w = tid >> 6;
  const int m = tid & 15;                       // G pixel-quad slot (m<=10) / pack pool (m>=11)
  const int chg = tid >> 4;                     // channel 0..31 for G/pack
  // x staging: 672 float2 slots (32ch x 21)
  const int u1c = tid / 21, u1q = tid - u1c * 21;
  const bool x2 = tid < 160;
  const int u2 = tid + 512;
  const int u2c = u2 / 21, u2q = u2 - u2c * 21;
  // pack mapping: threads with m>=11, 96 active slots (pixel, ch-half)
  const int pu = chg * 5 + (m - 11);
  const bool packer = (m >= 11) && (pu < 96);
  const int ppp = packer ? (pu >> 1) : 0, pgh = pu & 1;

  int r0 = bx - 1; if (r0 < 0) r0 = 0; if (r0 > 11) r0 = 11;
  const float* xb = x + (size_t)b * CDIM * NPIX + r0 * HIN;

  f32x4 acc[NT];
#pragma unroll
  for (int t2 = 0; t2 < NT; ++t2) acc[t2] = f32x4{0.f, 0.f, 0.f, 0.f};
  f32x4 gD = {0,0,0,0}, gR = {0,0,0,0}, gV = {0,0,0,0}, gX = {0,0,0,0}, gY = {0,0,0,0};

  auto XLOAD = [&](int ss, float2& v1, float2& v2) {
    const float* base = xb + (size_t)ss * 32 * NPIX;
    v1 = *(const float2*)(base + u1c * NPIX + 2 * u1q);
    if (x2) v2 = *(const float2*)(base + u2c * NPIX + 2 * u2q);
  };
  auto XSTORE = [&](int ss, float2 v1, float2 v2) {
    float* Pb = u.l.P[ss & 1];
    *(float2*)&Pb[u1c * PST + 2 * u1q] = v1;
    if (x2) *(float2*)&Pb[u2c * PST + 2 * u2q] = v2;
  };
  auto PACK = [&](int ss) {
    if (!packer) return;
    const float* Pb = u.l.P[ss & 1];
    const int tile = ppp >> 4, lr2 = ppp & 15;
    ushort* dst = u.l.Bf[ss & 1];
#pragma unroll
    for (int gsub = 0; gsub < 2; ++gsub) {
      const int g = pgh * 2 + gsub;
      uint uu[4];
#pragma unroll
      for (int p = 0; p < 4; ++p) {
        float v0 = Pb[(g * 8 + 2 * p) * PST + ppp];
        float v1 = Pb[(g * 8 + 2 * p + 1) * PST + ppp];
        uu[p] = (uint)__bfloat16_as_ushort(__float2bfloat16(v0)) |
                ((uint)__bfloat16_as_ushort(__float2bfloat16(v1)) << 16);
      }
      uint4 pk; pk.x = uu[0]; pk.y = uu[1]; pk.z = uu[2]; pk.w = uu[3];
      *(uint4*)&dst[((tile * 4 + g) * 16 + lr2) * 8] = pk;
    }
  };
  auto GACC = [&](int ss) {
    if (m > 10) return;
    const float* Pr = &u.l.P[ss & 1][chg * PST];
    f32x4 xs = *(const f32x4*)&Pr[4 * m];
    float x4 = Pr[4 * m + 4];
    gD[0] = fmaf(xs[0], xs[0], gD[0]); gD[1] = fmaf(xs[1], xs[1], gD[1]);
    gD[2] = fmaf(xs[2], xs[2], gD[2]); gD[3] = fmaf(xs[3], xs[3], gD[3]);
    gR[0] = fmaf(xs[0], xs[1], gR[0]); gR[1] = fmaf(xs[1], xs[2], gR[1]);
    gR[2] = fmaf(xs[2], xs[3], gR[2]); gR[3] = fmaf(xs[3], x4,    gR[3]);
    if (m < 7) {
      f32x4 ya = *(const f32x4*)&Pr[4 * m + 12];  // px 4m+12..15
      f32x4 yb = *(const f32x4*)&Pr[4 * m + 16];  // px 4m+16..19
      gV[0] = fmaf(xs[0], ya[2], gV[0]); gV[1] = fmaf(xs[1], ya[3], gV[1]);
      gV[2] = fmaf(xs[2], yb[0], gV[2]); gV[3] = fmaf(xs[3], yb[1], gV[3]);
      gX[0] = fmaf(xs[0], ya[3], gX[0]); gX[1] = fmaf(xs[1], yb[0], gX[1]);
      gX[2] = fmaf(xs[2], yb[1], gX[2]); gX[3] = fmaf(xs[3], yb[2], gX[3]);
      gY[0] = fmaf(xs[0], ya[1], gY[0]); gY[1] = fmaf(xs[1], ya[2], gY[1]);
      gY[2] = fmaf(xs[2], ya[3], gY[2]); gY[3] = fmaf(xs[3], yb[0], gY[3]);
    }
  };
  auto MF = [&](int ss) {
    const ushort* Ab = u.l.A[ss & 1];
    const ushort* Bb = u.l.Bf[ss & 1];
    short8 af = *(const short8*)&Ab[w * 512 + lane * 8];
#pragma unroll
    for (int tt = 0; tt < NT; ++tt) {
      short8 bfr = *(const short8*)&Bb[tt * 512 + lane * 8];
      acc[tt] = __builtin_amdgcn_mfma_f32_16x16x32_bf16(af, bfr, acc[tt], 0, 0, 0);
    }
  };

  // ---- prologue ----
  {
    // zero P pads [both bufs][32 ch][px 42..51]
    int z = tid;
#pragma unroll
    for (int it = 0; it < 2; ++it, z += 512) {
      if (z < 640) {
        int bb = z / 320, r = z - bb * 320;
        int c = r / 10, j = r - c * 10;
        u.l.P[bb][c * PST + 42 + j] = 0.f;
      }
    }
    if (tid < KDIM) csq_s[tid] = csq[tid];
    float2 a1, a2, b1v, b2v;
    XLOAD(0, a1, a2); XLOAD(1, b1v, b2v);
    uint4 av0 = *(const uint4*)(cbf + (size_t)tid * 8);
    XSTORE(0, a1, a2); XSTORE(1, b1v, b2v);
    *(uint4*)&u.l.A[0][tid * 8] = av0;
    __syncthreads();
    PACK(0); GACC(0);
    __syncthreads();
  }

  // ---- main loop: one barrier/step ----
  for (int s = 0; s < NSTEP; ++s) {
    const bool m1 = (s + 1) < NSTEP, m2 = (s + 2) < NSTEP;
    float2 q1, q2; uint4 av;
    if (m2) XLOAD(s + 2, q1, q2);
    if (m1) av = *(const uint4*)(cbf + (size_t)(s + 1) * 4096 + tid * 8);
    if (m1) { PACK(s + 1); GACC(s + 1); }
    MF(s);
    if (m2) XSTORE(s + 2, q1, q2);
    if (m1) *(uint4*)&u.l.A[(s + 1) & 1][tid * 8] = av;
    __syncthreads();
  }

  // ---- epilogue 1: G shfl-reduce (4 ch per wave) -> Gpart; RDs from acc ----
  {
    f32x4 vs0 = gD, vs1 = gR, vs2 = gV, vs3 = gX, vs4 = gY;
#pragma unroll
    for (int c = 0; c < 4; ++c) {
      vs0[c] += __shfl_xor(vs0[c], 16, 64); vs0[c] += __shfl_xor(vs0[c], 32, 64);
      vs1[c] += __shfl_xor(vs1[c], 16, 64); vs1[c] += __shfl_xor(vs1[c], 32, 64);
      vs2[c] += __shfl_xor(vs2[c], 16, 64); vs2[c] += __shfl_xor(vs2[c], 32, 64);
      vs3[c] += __shfl_xor(vs3[c], 16, 64); vs3[c] += __shfl_xor(vs3[c], 32, 64);
      vs4[c] += __shfl_xor(vs4[c], 16, 64); vs4[c] += __shfl_xor(vs4[c], 32, 64);
    }
    if (lane < 11) {
      float* gp = &u.e.Gpart[(w * 11 + lane) * 20];
      *(f32x4*)&gp[0]  = vs0; *(f32x4*)&gp[4]  = vs1; *(f32x4*)&gp[8]  = vs2;
      *(f32x4*)&gp[12] = vs3; *(f32x4*)&gp[16] = vs4;
    }
    const int lr = lane & 15, gsn = lane >> 4;
#pragma unroll
    for (int tt = 0; tt < NT; ++tt)
#pragma unroll
      for (int q = 0; q < 4; ++q)
        u.e.RDs[(w * 16 + gsn * 4 + q) * RDST + tt * 16 + lr] = acc[tt][q];
  }
  __syncthreads();

  // ---- epilogue 2: reduce Gpart over 8 waves -> Gs ----
  if (tid < 220) {
    const int mm = tid / 20, ii = tid - mm * 20;
    float v = 0.f;
#pragma unroll
    for (int ww = 0; ww < 8; ++ww) v += u.e.Gpart[(ww * 11 + mm) * 20 + ii];
    Gs[(ii >> 2) * 44 + 4 * mm + (ii & 3)] = v;
  }
  __syncthreads();

  // per-column folded bilinear taps
  auto COLW = [&](int col, int& p1, int& p3, float& w00, float& w01, float& w10, float& w11) {
    const int i2 = 2 * bx + (col >= 28 ? 1 : 0);
    const int j2 = col - (col >= 28 ? 28 : 0);
    float si = 0.5f * i2 - 0.25f, sj = 0.5f * j2 - 0.25f;
    float fif = floorf(si), fjf = floorf(sj);
    int ii = (int)fif, jj = (int)fjf;
    float fi = si - fif, fj = sj - fjf;
    int ia = ii < 0 ? 0 : ii; int ib = (ii + 1 > 13) ? 13 : ii + 1;
    int ja = jj < 0 ? 0 : jj; int jb = (jj + 1 > 13) ? 13 : jj + 1;
    w00 = (1.f - fi) * (1.f - fj); w01 = (1.f - fi) * fj;
    w10 = fi * (1.f - fj);         w11 = fi * fj;
    if (ib == ia) { w00 += w10; w01 += w11; w10 = 0.f; w11 = 0.f; }
    if (jb == ja) { w00 += w01; w10 += w11; w01 = 0.f; w11 = 0.f; }
    p1 = (ia - r0) * HIN + ja; p3 = (ib - r0) * HIN + ja;
  };

  // ---- epilogue 3: xsq (10-term Gram blend) + proj (RD row 113 blend) ----
  if (tid < BNC) {
    int p1, p3; float w00, w01, w10, w11;
    COLW(tid, p1, p3, w00, w01, w10, w11);
    const float* Gd = Gs, *Gr = Gs + 44, *Gv = Gs + 88, *Gx = Gs + 132, *Gy = Gs + 176;
    float xsq = w00 * w00 * Gd[p1] + w01 * w01 * Gd[p1 + 1]
              + w10 * w10 * Gd[p3] + w11 * w11 * Gd[p3 + 1]
              + 2.f * (w00 * w01 * Gr[p1] + w10 * w11 * Gr[p3]
                     + w00 * w10 * Gv[p1] + w01 * w11 * Gv[p1 + 1]
                     + w00 * w11 * Gx[p1] + w01 * w10 * Gy[p1 + 1]);
    const float* rp = &u.e.RDs[113 * RDST];
    float pj = w00 * rp[p1] + w01 * rp[p1 + 1] + w10 * rp[p3] + w11 * rp[p3 + 1];
    xsqs[tid] = xsq; projs[tid] = pj;
  }
  __syncthreads();

  // ---- epilogue 4: d2 -> -dist -> quad softmax (in Ss) ----
  if (tid < BNC * 4) {
    const int col = tid >> 2, sub = tid & 3;
    int p1, p3; float w00, w01, w10, w11;
    COLW(col, p1, p3, w00, w01, w10, w11);
    const float xq = xsqs[col];
    float mx = -1e30f;
    for (int k = sub; k < KDIM; k += 4) {
      const float* rk = &u.e.RDs[k * RDST];
      float dot = w00 * rk[p1] + w01 * rk[p1 + 1] + w10 * rk[p3] + w11 * rk[p3 + 1];
      float d2 = csq_s[k] + xq - 2.f * dot;
      float sv = -sqrtf(fmaxf(d2, 0.f));
      u.e.Ss[k * SST + col] = sv;
      mx = fmaxf(mx, sv);
    }
    mx = fmaxf(mx, __shfl_xor(mx, 1, 64));
    mx = fmaxf(mx, __shfl_xor(mx, 2, 64));
    float ssum = 0.f;
    for (int k = sub; k < KDIM; k += 4) {
      float e = __expf(u.e.Ss[k * SST + col] - mx);
      u.e.Ss[k * SST + col] = e;
      ssum += e;
    }
    ssum += __shfl_xor(ssum, 1, 64);
    ssum += __shfl_xor(ssum, 2, 64);
    const float rinv = 1.f / ssum;
    for (int k = sub; k < KDIM; k += 4) u.e.Ss[k * SST + col] *= rinv;
  }
  __syncthreads();

  // ---- epilogue 5: coalesced attn write ----
  {
    const int col2 = tid & 63, kr = tid >> 6;
    if (col2 < BNC) {
      float* op = attn_out + (size_t)b * KDIM * N2 + n0 + col2;
      for (int k = kr; k < KDIM; k += 8) op[(size_t)k * N2] = u.e.Ss[k * SST + col2];
    }
  }

  // ---- epilogue 6: logit partials ----
  if (tid < KC * 4) {
    const int k = tid >> 2, sub = tid & 3;
    float lg = 0.f;
    for (int c2 = sub; c2 < BNC; c2 += 4) lg = fmaf(u.e.Ss[k * SST + c2], projs[c2], lg);
    lg += __shfl_xor(lg, 1, 64);
    lg += __shfl_xor(lg, 2, 64);
    if (sub == 0) part[((size_t)b * NBX + bx) * KC + k] = lg;
  }
}

// ---------------- K4: reduce partials -> sigmoid -> concept_scores ----------------
__global__ void k_sig(const float* __restrict__ part, const float* __restrict__ cfcb,
                      float* __restrict__ cs_out) {
  int i = blockIdx.x * blockDim.x + threadIdx.x;
  if (i >= BDIM * KC) return;
  int b = i / KC, k = i % KC;
  float l = cfcb[0];
#pragma unroll
  for (int t = 0; t < NBX; ++t) l += part[((size_t)b * NBX + t) * KC + k];
  cs_out[i] = 1.f / (1.f + __expf(-l));
}

// ---------------- K5a: tmp[b,c] = sum_k cs[b,k] * concepts[k,c] ----------------
__global__ __launch_bounds__(256) void k_tmp(
    const float* __restrict__ concepts, const float* __restrict__ cs,
    float* __restrict__ tmp) {
  __shared__ float cs_s[KC];
  const int b = blockIdx.y;
  const int c = blockIdx.x * 256 + threadIdx.x;
  if (threadIdx.x < KC) cs_s[threadIdx.x] = cs[b * KC + threadIdx.x];
  __syncthreads();
  float a = 0.f;
#pragma unroll 8
  for (int k = 0; k < KC; ++k) a = fmaf(cs_s[k], concepts[(size_t)k * CDIM + c], a);
  tmp[(size_t)b * CDIM + c] = a;
}

// ---------------- K5b: preds[b,cls] = tmp[b,:].labw[cls,:] + labb ----------------
__global__ __launch_bounds__(256) void k_pred2(
    const float* __restrict__ labw, const float* __restrict__ labb,
    const float* __restrict__ tmp, float* __restrict__ preds) {
  const int w = blockIdx.x * 4 + (threadIdx.x >> 6);
  const int lane = threadIdx.x & 63;
  const int b = w / NCLS, cls = w % NCLS;
  if (b >= BDIM) return;
  const float* tr = tmp + (size_t)b * CDIM;
  const float* wr = labw + (size_t)cls * CDIM;
  float a = 0.f;
#pragma unroll
  for (int c0 = 0; c0 < CDIM; c0 += 256) {
    float4 t = *(const float4*)&tr[c0 + lane * 4];
    float4 v = *(const float4*)&wr[c0 + lane * 4];
    a += t.x * v.x + t.y * v.y + t.z * v.z + t.w * v.w;
  }
#pragma unroll
  for (int off = 32; off > 0; off >>= 1) a += __shfl_down(a, off, 64);
  if (lane == 0) preds[b * NCLS + cls] = a + labb[cls];
}

extern "C" void kernel_launch(void* const* d_in, const int* in_sizes, int n_in,
                              void* d_out, int out_size, void* d_ws, size_t ws_size,
                              hipStream_t stream) {
  const float* x        = (const float*)d_in[0];
  const float* concepts = (const float*)d_in[1];
  const float* cfcw     = (const float*)d_in[2];
  const float* cfcb     = (const float*)d_in[3];
  const float* labw     = (const float*)d_in[4];
  const float* labb     = (const float*)d_in[5];

  float* out    = (float*)d_out;
  float* sm_out = out;                                  // [32][113][784]
  float* cs_out = out + (size_t)BDIM * KDIM * N2;       // [32][112]
  float* pr_out = cs_out + (size_t)BDIM * KC;           // [32][200]

  char* ws = (char*)d_ws;
  float*  csq  = (float*)(ws + 0);          // 128 f32            -> 512 B
  float*  part = (float*)(ws + 512);        // 32*14*112 f32      -> 200,704 B
  ushort* cbf  = (ushort*)(ws + 201216);    // 128*2048 bf16      -> 524,288 B
  float*  tmp  = (float*)(ws + 725504);     // 32*2048 f32        -> 262,144 B

  k_prep <<<dim3(128), dim3(256), 0, stream>>>(concepts, cfcw, cbf, csq);
  k_fused<<<dim3(448), dim3(512), 0, stream>>>(x, cbf, csq, sm_out, part);
  k_sig  <<<dim3((BDIM * KC + 255) / 256), dim3(256), 0, stream>>>(part, cfcb, cs_out);
  k_tmp  <<<dim3(CDIM / 256, BDIM), dim3(256), 0, stream>>>(concepts, cs_out, tmp);
  k_pred2<<<dim3((BDIM * NCLS + 3) / 4), dim3(256), 0, stream>>>(labw, labb, tmp, pr_out);
}